// Round 1
// baseline (499.087 us; speedup 1.0000x reference)
//
#include <hip/hip_runtime.h>
#include <hip/hip_cooperative_groups.h>
#include <math.h>

// CALayer: out = x * sigmoid(w2 @ leakyrelu(w1 @ mean(x,HW) + b1) + b2)
// B=8, C=256, H=W=128, Cs=16
#define Bn 8
#define Cn 256
#define CSn 16
#define HWn 16384
#define PL4 4096            // float4 per plane
#define NEG_SLOPE 0.2f

typedef float f4v __attribute__((ext_vector_type(4)));
namespace cg = cooperative_groups;

// ---------------- Fused cooperative kernel: pool -> grid.sync -> gate -> scale
// grid = 2048 blocks x 256 thr = 8 blocks/CU x 256 CU (exact co-residency fit).
// __launch_bounds__(256, 8): 8 blocks/CU -> VGPR cap 64, guarantees cooperative
// launch validity.
__global__ __launch_bounds__(256, 8) void fused_kernel(
    const float* __restrict__ x,
    const float* __restrict__ w1, const float* __restrict__ b1,
    const float* __restrict__ w2, const float* __restrict__ b2,
    float* __restrict__ out, float* __restrict__ y) {
    const int bc = blockIdx.x;
    const int b = bc >> 8, c = bc & (Cn - 1);
    const int t = threadIdx.x;
    const f4v* xp = (const f4v*)x + (size_t)bc * PL4;

    // ---- Phase 1: global average pool of plane (b,c). Regular loads so x
    // allocates in L3 for the phase-3 re-read.
    float sum = 0.f;
    #pragma unroll
    for (int i = 0; i < 16; ++i) {
        f4v v = xp[t + i * 256];
        sum += (v.x + v.y) + (v.z + v.w);
    }
    #pragma unroll
    for (int off = 32; off; off >>= 1)
        sum += __shfl_down(sum, off, 64);
    __shared__ float sm[4];
    if ((t & 63) == 0) sm[t >> 6] = sum;
    __syncthreads();
    if (t == 0)
        y[bc] = (sm[0] + sm[1] + sm[2] + sm[3]) * (1.f / (float)HWn);

    cg::this_grid().sync();

    // ---- Phase 2: gate for (b,c); redundant per block but cheap (w1/w2 L2-hot).
    __shared__ float part[CSn * 17];
    __shared__ float gsh;
    {
        const int s = t >> 4, j = t & 15;            // 16 partials per squeeze-row
        const f4v* yb = (const f4v*)(y + b * Cn) + j * 4;
        const f4v* wr = (const f4v*)(w1 + s * Cn) + j * 4;
        float p = 0.f;
        #pragma unroll
        for (int k = 0; k < 4; ++k) {
            f4v a = yb[k], w = wr[k];
            p += (a.x * w.x + a.y * w.y) + (a.z * w.z + a.w * w.w);
        }
        part[s * 17 + j] = p;
    }
    __syncthreads();
    if (t < CSn) {
        float a = b1[t];
        #pragma unroll
        for (int j = 0; j < 16; ++j) a += part[t * 17 + j];
        float y1 = (a >= 0.f) ? a : NEG_SLOPE * a;
        float v = y1 * w2[c * CSn + t];
        // 16-lane tree reduce (lanes 0..15 of wave 0, all active in-branch)
        v += __shfl_xor(v, 8);
        v += __shfl_xor(v, 4);
        v += __shfl_xor(v, 2);
        v += __shfl_xor(v, 1);
        if (t == 0) gsh = 1.f / (1.f + __expf(-(v + b2[c])));
    }
    __syncthreads();
    const float g = gsh;

    // ---- Phase 3: scale the plane. Re-read should hit L3; nt stores avoid
    // evicting x from L3.
    f4v* op = (f4v*)out + (size_t)bc * PL4;
    #pragma unroll
    for (int i = 0; i < 16; ++i) {
        f4v v = xp[t + i * 256];
        v *= g;
        __builtin_nontemporal_store(v, &op[t + i * 256]);
    }
}

// ---------------- Fallback path (proven 258 µs): used only if cooperative
// launch is rejected (e.g. by graph capture).
__global__ __launch_bounds__(256) void pool_kernel(const float* __restrict__ x,
                                                   float* __restrict__ y) {
    const int bc = blockIdx.x;
    const f4v* xp = (const f4v*)x + (size_t)bc * PL4;
    const int t = threadIdx.x;
    float sum = 0.f;
    #pragma unroll
    for (int i = 0; i < 16; ++i) {
        f4v v = xp[t + i * 256];
        sum += (v.x + v.y) + (v.z + v.w);
    }
    #pragma unroll
    for (int off = 32; off; off >>= 1)
        sum += __shfl_down(sum, off, 64);
    __shared__ float sm[4];
    if ((t & 63) == 0) sm[t >> 6] = sum;
    __syncthreads();
    if (t == 0)
        y[bc] = (sm[0] + sm[1] + sm[2] + sm[3]) * (1.f / (float)HWn);
}

__global__ __launch_bounds__(256) void scale_kernel(const float* __restrict__ x,
                                                    const float* __restrict__ y,
                                                    const float* __restrict__ w1,
                                                    const float* __restrict__ b1,
                                                    const float* __restrict__ w2,
                                                    const float* __restrict__ b2,
                                                    float* __restrict__ out) {
    const int bc = blockIdx.x;
    const int b = bc >> 8, c = bc & (Cn - 1);
    const int t = threadIdx.x;

    __shared__ float part[CSn * 17];
    __shared__ float y1s[CSn];
    __shared__ float gsh;
    {
        const int s = t >> 4, j = t & 15;
        const float* yb = y  + b * Cn + j * 16;
        const float* wr = w1 + s * Cn + j * 16;
        float p = 0.f;
        #pragma unroll
        for (int k = 0; k < 16; ++k) p += yb[k] * wr[k];
        part[s * 17 + j] = p;
    }
    __syncthreads();
    if (t < CSn) {
        float a = b1[t];
        #pragma unroll
        for (int j = 0; j < 16; ++j) a += part[t * 17 + j];
        y1s[t] = (a >= 0.f) ? a : NEG_SLOPE * a;
    }
    __syncthreads();
    if (t == 0) {
        float a = b2[c];
        #pragma unroll
        for (int s = 0; s < CSn; ++s) a += y1s[s] * w2[c * CSn + s];
        gsh = 1.f / (1.f + __expf(-a));
    }
    __syncthreads();
    const float g = gsh;

    const f4v* xp = (const f4v*)x + (size_t)bc * PL4;
    f4v* op = (f4v*)out + (size_t)bc * PL4;
    #pragma unroll
    for (int i = 0; i < 16; ++i) {
        f4v v = xp[t + i * 256];
        v *= g;
        __builtin_nontemporal_store(v, &op[t + i * 256]);
    }
}

extern "C" void kernel_launch(void* const* d_in, const int* in_sizes, int n_in,
                              void* d_out, int out_size, void* d_ws, size_t ws_size,
                              hipStream_t stream) {
    const float* x  = (const float*)d_in[0];
    const float* w1 = (const float*)d_in[1];
    const float* b1 = (const float*)d_in[2];
    const float* w2 = (const float*)d_in[3];
    const float* b2 = (const float*)d_in[4];
    float* out = (float*)d_out;
    float* y   = (float*)d_ws;      // [B*C] = 2048 floats

    void* args[] = {(void*)&x, (void*)&w1, (void*)&b1, (void*)&w2, (void*)&b2,
                    (void*)&out, (void*)&y};
    hipError_t err = hipLaunchCooperativeKernel((const void*)fused_kernel,
                                                dim3(Bn * Cn), dim3(256),
                                                args, 0, stream);
    if (err != hipSuccess) {
        (void)hipGetLastError();   // clear sticky error, fall back
        pool_kernel<<<Bn * Cn, 256, 0, stream>>>(x, y);
        scale_kernel<<<Bn * Cn, 256, 0, stream>>>(x, y, w1, b1, w2, b2, out);
    }
}

// Round 2
// 437.814 us; speedup vs baseline: 1.1400x; 1.1400x over previous
//
#include <hip/hip_runtime.h>
#include <math.h>

// CALayer: out = x * sigmoid(w2 @ leakyrelu(w1 @ mean(x,HW) + b1) + b2)
// B=8, C=256, H=W=128, Cs=16
#define Bn 8
#define Cn 256
#define CSn 16
#define HWn 16384
#define PL4 4096            // float4 per plane
#define NEG_SLOPE 0.2f

typedef float f4v __attribute__((ext_vector_type(4)));

// ---------------- Kernel 1: pool + last-block-per-batch gate -----------------
// One block per (b,c) plane. After writing y[bc], each block atomically bumps
// cnt[b]; the single block that arrives last (old==255) computes the 256 gates
// for batch b. No block ever waits on another -> no residency assumption, no
// deadlock possible (G16-safe: release fence + device-scope RMW + agent-scope
// loads of y).
__global__ __launch_bounds__(256) void pool_gate_kernel(
    const float* __restrict__ x,
    const float* __restrict__ w1, const float* __restrict__ b1,
    const float* __restrict__ w2, const float* __restrict__ b2,
    float* __restrict__ y, float* __restrict__ g,
    unsigned* __restrict__ cnt) {
    const int bc = blockIdx.x;
    const int b = bc >> 8;
    const int t = threadIdx.x;
    const f4v* xp = (const f4v*)x + (size_t)bc * PL4;

    // ---- global average pool of plane (b,c); regular loads so x lands in L3
    float sum = 0.f;
    #pragma unroll
    for (int i = 0; i < 16; ++i) {
        f4v v = xp[t + i * 256];
        sum += (v.x + v.y) + (v.z + v.w);
    }
    #pragma unroll
    for (int off = 32; off; off >>= 1)
        sum += __shfl_down(sum, off, 64);
    __shared__ float sm[4];
    __shared__ int lastFlag;
    if ((t & 63) == 0) sm[t >> 6] = sum;
    __syncthreads();
    if (t == 0) {
        y[bc] = (sm[0] + sm[1] + sm[2] + sm[3]) * (1.f / (float)HWn);
        __threadfence();                        // release y before the RMW
        unsigned old = __hip_atomic_fetch_add(&cnt[b], 1u, __ATOMIC_ACQ_REL,
                                              __HIP_MEMORY_SCOPE_AGENT);
        lastFlag = (old == (unsigned)(Cn - 1));
    }
    __syncthreads();
    if (!lastFlag) return;

    // ---- last block of batch b: gates for all 256 channels of this batch
    __shared__ float ys[Cn];
    __shared__ float part[CSn * 17];
    __shared__ float y1s[CSn];
    // agent-scope loads: bypass any stale per-XCD cached copies of y
    ys[t] = __hip_atomic_load(&y[b * Cn + t], __ATOMIC_RELAXED,
                              __HIP_MEMORY_SCOPE_AGENT);
    __syncthreads();
    {
        const int s = t >> 4, j = t & 15;        // 16 partials per squeeze-row
        const float* wr = w1 + s * Cn + j * 16;
        const float* yv = ys + j * 16;
        float p = 0.f;
        #pragma unroll
        for (int k = 0; k < 16; ++k) p += yv[k] * wr[k];
        part[s * 17 + j] = p;
    }
    __syncthreads();
    if (t < CSn) {
        float a = b1[t];
        #pragma unroll
        for (int j = 0; j < 16; ++j) a += part[t * 17 + j];
        y1s[t] = (a >= 0.f) ? a : NEG_SLOPE * a;
    }
    __syncthreads();
    {
        float a = b2[t];
        const float* wr = w2 + t * CSn;
        #pragma unroll
        for (int s = 0; s < CSn; ++s) a += y1s[s] * wr[s];
        g[b * Cn + t] = 1.f / (1.f + __expf(-a));
    }
}

// ---------------- Kernel 2: pure-stream channel scale ------------------------
// No barriers, no preamble: one uniform scalar load of the gate, then
// load-mul-ntstore. x re-read hits L3 (verified round 1: FETCH 143.7 MB);
// nt stores keep out from evicting x.
__global__ __launch_bounds__(256) void scale_kernel(
    const float* __restrict__ x, const float* __restrict__ g,
    float* __restrict__ out) {
    const int bc = blockIdx.x;
    const int t = threadIdx.x;
    const float gv = g[bc];                      // uniform -> scalar load
    const f4v* xp = (const f4v*)x + (size_t)bc * PL4;
    f4v* op = (f4v*)out + (size_t)bc * PL4;
    #pragma unroll
    for (int i = 0; i < 16; ++i) {
        f4v v = xp[t + i * 256];
        v *= gv;
        __builtin_nontemporal_store(v, &op[t + i * 256]);
    }
}

extern "C" void kernel_launch(void* const* d_in, const int* in_sizes, int n_in,
                              void* d_out, int out_size, void* d_ws, size_t ws_size,
                              hipStream_t stream) {
    const float* x  = (const float*)d_in[0];
    const float* w1 = (const float*)d_in[1];
    const float* b1 = (const float*)d_in[2];
    const float* w2 = (const float*)d_in[3];
    const float* b2 = (const float*)d_in[4];
    float* out = (float*)d_out;
    float* y   = (float*)d_ws;                   // [2048] floats
    float* g   = y + Bn * Cn;                    // [2048] floats
    unsigned* cnt = (unsigned*)(g + Bn * Cn);    // [8] uints (ws is poisoned
                                                 // each iter -> must re-zero)

    hipMemsetAsync(cnt, 0, Bn * sizeof(unsigned), stream);
    pool_gate_kernel<<<Bn * Cn, 256, 0, stream>>>(x, w1, b1, w2, b2, y, g, cnt);
    scale_kernel<<<Bn * Cn, 256, 0, stream>>>(x, g, out);
}

// Round 3
// 257.949 us; speedup vs baseline: 1.9348x; 1.6973x over previous
//
#include <hip/hip_runtime.h>
#include <math.h>

// CALayer: out = x * sigmoid(w2 @ leakyrelu(w1 @ mean(x,HW) + b1) + b2)
// B=8, C=256, H=W=128, Cs=16
#define Bn 8
#define Cn 256
#define CSn 16
#define HWn 16384
#define PL4 4096            // float4 per plane
#define NEG_SLOPE 0.2f

typedef float f4v __attribute__((ext_vector_type(4)));

// ---------------- Kernel 1: global average pool, one block per (b,c) plane ----
// Regular (cached) loads so x allocates in L3 for kernel 3's re-read.
__global__ __launch_bounds__(256) void pool_kernel(const float* __restrict__ x,
                                                   float* __restrict__ y) {
    const int bc = blockIdx.x;
    const f4v* xp = (const f4v*)x + (size_t)bc * PL4;
    const int t = threadIdx.x;
    float sum = 0.f;
    #pragma unroll
    for (int i = 0; i < 16; ++i) {
        f4v v = xp[t + i * 256];
        sum += (v.x + v.y) + (v.z + v.w);
    }
    #pragma unroll
    for (int off = 32; off; off >>= 1)
        sum += __shfl_down(sum, off, 64);
    __shared__ float sm[4];
    if ((t & 63) == 0) sm[t >> 6] = sum;
    __syncthreads();
    if (t == 0)
        y[bc] = (sm[0] + sm[1] + sm[2] + sm[3]) * (1.f / (float)HWn);
}

// ---------------- Kernel 2: gate, one block per batch (8 blocks) --------------
// Kernel-boundary ordering = free device-wide fence (round 2 lesson: explicit
// per-block threadfence+atomic cost ~180 us in coherence ops).
__global__ __launch_bounds__(256) void gate_kernel(
    const float* __restrict__ y,
    const float* __restrict__ w1, const float* __restrict__ b1,
    const float* __restrict__ w2, const float* __restrict__ b2,
    float* __restrict__ g) {
    const int b = blockIdx.x;
    const int t = threadIdx.x;
    __shared__ float part[CSn * 17];
    __shared__ float y1s[CSn];
    {
        const int s = t >> 4, j = t & 15;        // 16 partials per squeeze-row
        const float* yb = y  + b * Cn + j * 16;
        const float* wr = w1 + s * Cn + j * 16;
        float p = 0.f;
        #pragma unroll
        for (int k = 0; k < 16; ++k) p += yb[k] * wr[k];
        part[s * 17 + j] = p;
    }
    __syncthreads();
    if (t < CSn) {
        float a = b1[t];
        #pragma unroll
        for (int j = 0; j < 16; ++j) a += part[t * 17 + j];
        y1s[t] = (a >= 0.f) ? a : NEG_SLOPE * a;
    }
    __syncthreads();
    {
        float a = b2[t];
        const float* wr = w2 + t * CSn;
        #pragma unroll
        for (int s = 0; s < CSn; ++s) a += y1s[s] * wr[s];
        g[b * Cn + t] = 1.f / (1.f + __expf(-a));
    }
}

// ---------------- Kernel 3: pure-stream channel scale ------------------------
// No barriers, no preamble: uniform scalar gate load, then load-mul-ntstore.
// x re-read hits L3 (verified round 1: FETCH 143.7 MB for read-x-twice);
// nt stores keep out from evicting x.
__global__ __launch_bounds__(256) void scale_kernel(
    const float* __restrict__ x, const float* __restrict__ g,
    float* __restrict__ out) {
    const int bc = blockIdx.x;
    const int t = threadIdx.x;
    const float gv = g[bc];
    const f4v* xp = (const f4v*)x + (size_t)bc * PL4;
    f4v* op = (f4v*)out + (size_t)bc * PL4;
    #pragma unroll
    for (int i = 0; i < 16; ++i) {
        f4v v = xp[t + i * 256];
        v *= gv;
        __builtin_nontemporal_store(v, &op[t + i * 256]);
    }
}

extern "C" void kernel_launch(void* const* d_in, const int* in_sizes, int n_in,
                              void* d_out, int out_size, void* d_ws, size_t ws_size,
                              hipStream_t stream) {
    const float* x  = (const float*)d_in[0];
    const float* w1 = (const float*)d_in[1];
    const float* b1 = (const float*)d_in[2];
    const float* w2 = (const float*)d_in[3];
    const float* b2 = (const float*)d_in[4];
    float* out = (float*)d_out;
    float* y   = (float*)d_ws;                   // [2048] floats
    float* g   = y + Bn * Cn;                    // [2048] floats

    pool_kernel<<<Bn * Cn, 256, 0, stream>>>(x, y);
    gate_kernel<<<Bn, 256, 0, stream>>>(y, w1, b1, w2, b2, g);
    scale_kernel<<<Bn * Cn, 256, 0, stream>>>(x, g, out);
}

// Round 4
// 257.357 us; speedup vs baseline: 1.9393x; 1.0023x over previous
//
#include <hip/hip_runtime.h>
#include <math.h>

// CALayer: out = x * sigmoid(w2 @ leakyrelu(w1 @ mean(x,HW) + b1) + b2)
// B=8, C=256, H=W=128, Cs=16
#define Bn 8
#define Cn 256
#define CSn 16
#define HWn 16384
#define PL4 4096            // float4 per plane
#define NEG_SLOPE 0.2f

typedef float f4v __attribute__((ext_vector_type(4)));

// ---------------- Kernel 1: global average pool, one block per (b,c) plane ----
// 8-deep load batches: >=8 float4 loads in flight per wave (16 KB/CU at 32
// waves/CU) to cover ~900-cycle HBM latency; VGPR stays <=64 so occupancy is
// unaffected. Regular (cached) loads so x allocates in L3 for kernel 3.
__global__ __launch_bounds__(256) void pool_kernel(const float* __restrict__ x,
                                                   float* __restrict__ y) {
    const int bc = blockIdx.x;
    const f4v* xp = (const f4v*)x + (size_t)bc * PL4;
    const int t = threadIdx.x;
    f4v acc = {0.f, 0.f, 0.f, 0.f};
    #pragma unroll
    for (int h = 0; h < 2; ++h) {
        f4v v[8];                                 // compile-time indexed (rule #20)
        #pragma unroll
        for (int j = 0; j < 8; ++j) v[j] = xp[t + (h * 8 + j) * 256];
        #pragma unroll
        for (int j = 0; j < 8; ++j) acc += v[j];
    }
    float sum = (acc.x + acc.y) + (acc.z + acc.w);
    #pragma unroll
    for (int off = 32; off; off >>= 1)
        sum += __shfl_down(sum, off, 64);
    __shared__ float sm[4];
    if ((t & 63) == 0) sm[t >> 6] = sum;
    __syncthreads();
    if (t == 0)
        y[bc] = (sm[0] + sm[1] + sm[2] + sm[3]) * (1.f / (float)HWn);
}

// ---------------- Kernel 2: gate, one block per batch (8 blocks) --------------
// Kernel-boundary ordering = free device-wide fence (round 2 lesson: explicit
// per-block threadfence+atomic cost ~180 us in coherence ops).
__global__ __launch_bounds__(256) void gate_kernel(
    const float* __restrict__ y,
    const float* __restrict__ w1, const float* __restrict__ b1,
    const float* __restrict__ w2, const float* __restrict__ b2,
    float* __restrict__ g) {
    const int b = blockIdx.x;
    const int t = threadIdx.x;
    __shared__ float part[CSn * 17];
    __shared__ float y1s[CSn];
    {
        const int s = t >> 4, j = t & 15;        // 16 partials per squeeze-row
        const float* yb = y  + b * Cn + j * 16;
        const float* wr = w1 + s * Cn + j * 16;
        float p = 0.f;
        #pragma unroll
        for (int k = 0; k < 16; ++k) p += yb[k] * wr[k];
        part[s * 17 + j] = p;
    }
    __syncthreads();
    if (t < CSn) {
        float a = b1[t];
        #pragma unroll
        for (int j = 0; j < 16; ++j) a += part[t * 17 + j];
        y1s[t] = (a >= 0.f) ? a : NEG_SLOPE * a;
    }
    __syncthreads();
    {
        float a = b2[t];
        const float* wr = w2 + t * CSn;
        #pragma unroll
        for (int s = 0; s < CSn; ++s) a += y1s[s] * wr[s];
        g[b * Cn + t] = 1.f / (1.f + __expf(-a));
    }
}

// ---------------- Kernel 3: pure-stream channel scale ------------------------
// Same 8-deep batching for the x re-read (L3-hit, verified round 1: FETCH
// 143.7 MB for read-x-twice, but L3 latency still needs MLP). nt stores keep
// out from evicting x.
__global__ __launch_bounds__(256) void scale_kernel(
    const float* __restrict__ x, const float* __restrict__ g,
    float* __restrict__ out) {
    const int bc = blockIdx.x;
    const int t = threadIdx.x;
    const float gv = g[bc];
    const f4v* xp = (const f4v*)x + (size_t)bc * PL4;
    f4v* op = (f4v*)out + (size_t)bc * PL4;
    #pragma unroll
    for (int h = 0; h < 2; ++h) {
        f4v v[8];                                 // compile-time indexed
        #pragma unroll
        for (int j = 0; j < 8; ++j) v[j] = xp[t + (h * 8 + j) * 256];
        #pragma unroll
        for (int j = 0; j < 8; ++j) {
            v[j] *= gv;
            __builtin_nontemporal_store(v[j], &op[t + (h * 8 + j) * 256]);
        }
    }
}

extern "C" void kernel_launch(void* const* d_in, const int* in_sizes, int n_in,
                              void* d_out, int out_size, void* d_ws, size_t ws_size,
                              hipStream_t stream) {
    const float* x  = (const float*)d_in[0];
    const float* w1 = (const float*)d_in[1];
    const float* b1 = (const float*)d_in[2];
    const float* w2 = (const float*)d_in[3];
    const float* b2 = (const float*)d_in[4];
    float* out = (float*)d_out;
    float* y   = (float*)d_ws;                   // [2048] floats
    float* g   = y + Bn * Cn;                    // [2048] floats

    pool_kernel<<<Bn * Cn, 256, 0, stream>>>(x, y);
    gate_kernel<<<Bn, 256, 0, stream>>>(y, w1, b1, w2, b2, g);
    scale_kernel<<<Bn * Cn, 256, 0, stream>>>(x, g, out);
}